// Round 3
// baseline (130.905 us; speedup 1.0000x reference)
//
#include <hip/hip_runtime.h>
#include <math.h>
#include <stdint.h>

// Problem dims (fixed by reference setup_inputs)
#define BB 4
#define CC 8
#define PP 20
#define AA 30
#define SS 4
#define TT 2048
#define NB 18

#define TC 256                  // t-chunk per block (K-extent)
#define NTC (TT / TC)           // 8 t-chunks
#define NPG 10                  // (fallback kernel) p-groups of 2
#define NPAIR (PP / 2)          // 10 p-pairs per block
#define WSTR 260                // f16 row stride: 520 B -> 2-way bank alias (free), 8B-aligned
#define NTH 256                 // 4 waves: (p_local, k_half)

#define DIST_ELEMS (BB * CC * SS * PP * NB * AA)   // 1,382,400
#define DIST_BYTES ((size_t)DIST_ELEMS * 4)        // 5,529,600 B

typedef _Float16 half4_t __attribute__((ext_vector_type(4)));
typedef _Float16 half8_t __attribute__((ext_vector_type(8)));
typedef float f32x16 __attribute__((ext_vector_type(16)));

__device__ __forceinline__ void weight_top2(float x, int& n0, int& n1,
                                            float& w0, float& w1)
{
    const float PI_F  = 3.14159265358979323846f;
    const float INV_H = 2.8647913f;           // 18 / (2*pi)
    const float H     = 0.34906585f;          // 2*pi / 18
    const float INV_T = 100.0f;
    float u = (x + PI_F) * INV_H;             // in [0, 18]
    n0 = (int)floorf(u);
    n0 = n0 < 0 ? 0 : (n0 > NB - 1 ? NB - 1 : n0);
    float f  = u - (float)n0 - 0.5f;          // [-0.5, 0.5]
    float af = fabsf(f);
    n1 = n0 + (f >= 0.0f ? 1 : -1);
    float e;
    if (n1 < 0) {                             // reference's unwrapped low edge: w1 ~ 7e-16
        e = 0.0f; n1 = NB;                    // dump row (rows >= 18 never extracted)
    } else {
        if (n1 == NB) n1 = 0;                 // positive wrap: same gap formula
        e = __expf(-(H * (1.0f - 2.0f * af)) * INV_T);
    }
    w0 = 1.0f / (1.0f + e);
    w1 = 1.0f - w0;
}

// ---------------------------------------------------------------------------
// Kernel 1: block = (bc, s, tc). ampT staged ONCE, reused across all 20 p.
// Partial dist accumulated via global f32 atomics into d_ws.
// ---------------------------------------------------------------------------
__global__ __launch_bounds__(NTH)
void mi_partial_kernel(const float* __restrict__ phase,
                       const float* __restrict__ amp,
                       float* __restrict__ dist)
{
    __shared__ _Float16 Wl[2][32 * WSTR];     // 33,280 B (rows 18..31 dump/garbage)
    __shared__ _Float16 ampT[32 * WSTR];      // 16,640 B (rows 30,31 uninit, cols unused)

    const int tid = threadIdx.x;
    const int blk = blockIdx.x;
    const int tc  = blk & (NTC - 1);
    const int s   = (blk >> 3) & (SS - 1);
    const int bc  = blk >> 5;                 // b*CC + c

    const float* am = amp + (size_t)bc * (AA * SS * TT) + (size_t)s * TT + tc * TC;
    const float* phb = phase + (size_t)(bc * PP) * (SS * TT) + (size_t)s * TT + tc * TC;
    float* db = dist + (size_t)(bc * SS + s) * (PP * NB * AA);

    const int wv   = tid >> 6;                // 0..3
    const int lane = tid & 63;
    const int mpl  = wv >> 1;                 // wave's local p within pair
    const int mkh  = wv & 1;                  // wave's K-half of the chunk
    const int mrow = lane & 31;               // A n-row / B a-col
    const int mlh  = lane >> 5;

    // ---- stage amp chunk transposed -> f16 ampT[a][tt] (once per block) ----
    for (int i = tid; i < AA * (TC / 4); i += NTH) {
        int a = i >> 6;                       // TC/4 == 64
        int q = i & 63;
        const float4 v = *(const float4*)&am[(size_t)a * (SS * TT) + q * 4];
        half4_t h = { (_Float16)v.x, (_Float16)v.y, (_Float16)v.z, (_Float16)v.w };
        *(half4_t*)&ampT[a * WSTR + q * 4] = h;
    }

    // ---- register-prefetch phase values for pair 0 ----
    float phv[2];
    phv[0] = phb[(size_t)0 * (SS * TT) + tid];
    phv[1] = phb[(size_t)1 * (SS * TT) + tid];

    const f32x16 kZero = {};
    f32x16 acc = {};

    for (int pp = 0; pp < NPAIR; ++pp) {
        // ---- phase Z: zero W rows 0..17, both p (vectorized) ----
        for (int i = tid; i < 2 * 585; i += NTH) {   // 585 uint4 = 18*260 f16
            int pl = i / 585;
            int w  = i - pl * 585;
            ((uint4*)&Wl[pl][0])[w] = make_uint4(0u, 0u, 0u, 0u);
        }
        __syncthreads();                      // bar_z: zeroing done

        // ---- phase S: prefetch(pp+1) + atomics(pp-1) + weights + scatter ----
        float nphv0 = 0.0f, nphv1 = 0.0f;
        if (pp + 1 < NPAIR) {                 // issue loads earliest
            nphv0 = phb[(size_t)((pp + 1) * 2 + 0) * (SS * TT) + tid];
            nphv1 = phb[(size_t)((pp + 1) * 2 + 1) * (SS * TT) + tid];
        }
        if (pp > 0) {                         // fire-and-forget adds for pair pp-1
            #pragma unroll
            for (int r = 0; r < 16; ++r) {
                int row = (r & 3) + 8 * (r >> 2) + 4 * mlh;  // HW-verified C/D layout
                if (row < NB && mrow < AA)
                    atomicAdd(&db[((size_t)((pp - 1) * 2 + mpl) * NB + row) * AA + mrow],
                              acc[r]);
            }
        }
        acc = kZero;
        #pragma unroll
        for (int k = 0; k < 2; ++k) {         // expf chain overlaps atomic/prefetch drain
            int n0, n1; float w0, w1;
            weight_top2(phv[k], n0, n1, w0, w1);
            Wl[k][n0 * WSTR + tid] = (_Float16)w0;
            Wl[k][n1 * WSTR + tid] = (_Float16)w1;
        }
        phv[0] = nphv0; phv[1] = nphv1;
        __syncthreads();                      // bar_w: W ready (drains prefetch+atomics)

        // ---- phase M: 8 K-steps of 32x32x16 MFMA ----
        #pragma unroll
        for (int ks = 0; ks < 8; ++ks) {
            int t0 = mkh * 128 + ks * 16 + mlh * 8;
            const _Float16* Ab = &Wl[mpl][mrow * WSTR + t0];
            const _Float16* Bb = &ampT[mrow * WSTR + t0];
            half4_t a0 = *(const half4_t*)Ab;
            half4_t a1 = *(const half4_t*)(Ab + 4);
            half4_t b0 = *(const half4_t*)Bb;
            half4_t b1 = *(const half4_t*)(Bb + 4);
            half8_t av = __builtin_shufflevector(a0, a1, 0, 1, 2, 3, 4, 5, 6, 7);
            half8_t bv = __builtin_shufflevector(b0, b1, 0, 1, 2, 3, 4, 5, 6, 7);
            acc = __builtin_amdgcn_mfma_f32_32x32x16_f16(av, bv, acc, 0, 0, 0);
        }
        __syncthreads();                      // bar_m: W reads done before next zero
    }

    // ---- tail: atomics for the last pair ----
    #pragma unroll
    for (int r = 0; r < 16; ++r) {
        int row = (r & 3) + 8 * (r >> 2) + 4 * mlh;
        if (row < NB && mrow < AA)
            atomicAdd(&db[((size_t)((NPAIR - 1) * 2 + mpl) * NB + row) * AA + mrow],
                      acc[r]);
    }
}

// ---------------------------------------------------------------------------
// Kernel 2: entropy epilogue. One thread per output element (bcs, p, a).
// ---------------------------------------------------------------------------
__global__ __launch_bounds__(256)
void mi_entropy_kernel(const float* __restrict__ dist, float* __restrict__ out)
{
    int i = blockIdx.x * 256 + threadIdx.x;   // 0 .. 76799, ordered (bcs, p, a)
    int a  = i % AA;
    int rp = i / AA;                          // bcs*PP + p
    const float* dr = dist + (size_t)rp * (NB * AA) + a;
    float v[NB], tot = 0.0f;
    #pragma unroll
    for (int n = 0; n < NB; ++n) { v[n] = dr[n * AA]; tot += v[n]; }
    float inv = 1.0f / (tot + 1e-10f);
    float ne = 0.0f;
    #pragma unroll
    for (int n = 0; n < NB; ++n) {
        float pv = fmaxf(v[n] * inv, 1e-10f);
        ne += pv * logf(pv);
    }
    out[i] = 1.0f + ne * 0.345975362f;        // 1/log(18)
}

// ---------------------------------------------------------------------------
// Fallback (round-2 single-kernel path) if ws_size is too small.
// ---------------------------------------------------------------------------
__global__ __launch_bounds__(NTH)
void mi_mfma_kernel(const float* __restrict__ phase,
                    const float* __restrict__ amp,
                    float* __restrict__ out)
{
    __shared__ _Float16 Wl[2][32 * WSTR];
    __shared__ _Float16 ampT[32 * WSTR];

    const int tid  = threadIdx.x;
    const int blk  = blockIdx.x;
    const int pg   = blk % NPG;
    const int s    = (blk / NPG) & (SS - 1);
    const int bc   = blk / (NPG * SS);

    const float* am = amp + (size_t)bc * (AA * SS * TT) + (size_t)s * TT;

    const int wv   = tid >> 6;
    const int lane = tid & 63;
    const int mpl  = wv >> 1;
    const int mkh  = wv & 1;
    const int mrow = lane & 31;
    const int mlh  = lane >> 5;

    f32x16 acc = {};

    for (int c = 0; c < NTC; ++c) {
        __syncthreads();
        for (int i = tid; i < 2 * 585; i += NTH) {
            int pl = i / 585;
            int w  = i - pl * 585;
            ((uint4*)&Wl[pl][0])[w] = make_uint4(0u, 0u, 0u, 0u);
        }
        for (int i = tid; i < AA * (TC / 4); i += NTH) {
            int a = i >> 6;
            int q = i & 63;
            const float4 v = *(const float4*)&am[(size_t)a * (SS * TT) + c * TC + q * 4];
            half4_t h = { (_Float16)v.x, (_Float16)v.y, (_Float16)v.z, (_Float16)v.w };
            *(half4_t*)&ampT[a * WSTR + q * 4] = h;
        }
        __syncthreads();
        for (int k = 0; k < 2; ++k) {
            int it = tid + (k << 8);
            int pl = it >> 8;
            int tt = it & (TC - 1);
            int p  = pg * 2 + pl;
            float x = phase[((size_t)(bc * PP + p) * SS + s) * TT + c * TC + tt];
            int n0, n1; float w0, w1;
            weight_top2(x, n0, n1, w0, w1);
            Wl[pl][n0 * WSTR + tt] = (_Float16)w0;
            Wl[pl][n1 * WSTR + tt] = (_Float16)w1;
        }
        __syncthreads();
        #pragma unroll
        for (int ks = 0; ks < 8; ++ks) {
            int t0 = mkh * 128 + ks * 16 + mlh * 8;
            const _Float16* Ab = &Wl[mpl][mrow * WSTR + t0];
            const _Float16* Bb = &ampT[mrow * WSTR + t0];
            half4_t a0 = *(const half4_t*)Ab;
            half4_t a1 = *(const half4_t*)(Ab + 4);
            half4_t b0 = *(const half4_t*)Bb;
            half4_t b1 = *(const half4_t*)(Bb + 4);
            half8_t av = __builtin_shufflevector(a0, a1, 0, 1, 2, 3, 4, 5, 6, 7);
            half8_t bv = __builtin_shufflevector(b0, b1, 0, 1, 2, 3, 4, 5, 6, 7);
            acc = __builtin_amdgcn_mfma_f32_32x32x16_f16(av, bv, acc, 0, 0, 0);
        }
    }
    __syncthreads();

    float* dist = (float*)&ampT[0];
    #pragma unroll
    for (int r = 0; r < 16; ++r) {
        int row = (r & 3) + 8 * (r >> 2) + 4 * mlh;
        if (row < NB)
            dist[(((mpl << 1) | mkh) * NB + row) * 33 + mrow] = acc[r];
    }
    __syncthreads();

    if (tid < 2 * AA) {
        int pl = tid / AA;
        int a  = tid - pl * AA;
        float dn[NB], tot = 0.0f;
        #pragma unroll
        for (int n = 0; n < NB; ++n) {
            dn[n] = dist[((pl * 2 + 0) * NB + n) * 33 + a]
                  + dist[((pl * 2 + 1) * NB + n) * 33 + a];
            tot += dn[n];
        }
        float inv = 1.0f / (tot + 1e-10f);
        float ne = 0.0f;
        #pragma unroll
        for (int n = 0; n < NB; ++n) {
            float pv = fmaxf(dn[n] * inv, 1e-10f);
            ne += pv * logf(pv);
        }
        int p = pg * 2 + pl;
        out[((size_t)bc * SS + s) * (PP * AA) + p * AA + a] = 1.0f + ne * 0.345975362f;
    }
}

extern "C" void kernel_launch(void* const* d_in, const int* in_sizes, int n_in,
                              void* d_out, int out_size, void* d_ws, size_t ws_size,
                              hipStream_t stream)
{
    const float* phase = (const float*)d_in[0];
    const float* amp   = (const float*)d_in[1];
    float* out = (float*)d_out;

    if (ws_size >= DIST_BYTES) {
        float* dist = (float*)d_ws;
        hipMemsetAsync(d_ws, 0, DIST_BYTES, stream);
        hipLaunchKernelGGL(mi_partial_kernel, dim3(BB * CC * SS * NTC), dim3(NTH),
                           0, stream, phase, amp, dist);
        hipLaunchKernelGGL(mi_entropy_kernel, dim3((BB * CC * SS * PP * AA) / 256),
                           dim3(256), 0, stream, dist, out);
    } else {
        hipLaunchKernelGGL(mi_mfma_kernel, dim3(BB * CC * SS * NPG), dim3(NTH),
                           0, stream, phase, amp, out);
    }
}

// Round 4
// 70.134 us; speedup vs baseline: 1.8665x; 1.8665x over previous
//
#include <hip/hip_runtime.h>
#include <math.h>
#include <stdint.h>

// Problem dims (fixed by reference setup_inputs)
#define BB 4
#define CC 8
#define PP 20
#define AA 30
#define SS 4
#define TT 2048
#define NB 18

#define TC 256                  // t-chunk per stage-1 block
#define NTC (TT / TC)           // 8 t-chunks
#define NPG 10                  // (fallback kernel) p-groups of 2
#define NPAIR (PP / 2)          // 10 p-pairs per stage-1 block
#define WSTR 260                // f16 row stride: 520 B -> 2-way bank alias (free), 8B-aligned
#define NTH 256                 // 4 waves: (p_local, k_half)
#define DUMPF 2340              // float offset of dump scratch inside Wl[pl] (= row 18)

// Partial dist workspace: [bcs=128][tc=8][p=20][row=18][col=32] f32
#define WS2_BYTES ((size_t)BB * CC * SS * NTC * PP * 18 * 32 * 4)   // 47,185,920

typedef _Float16 half4_t __attribute__((ext_vector_type(4)));
typedef _Float16 half8_t __attribute__((ext_vector_type(8)));
typedef float f32x16 __attribute__((ext_vector_type(16)));

__device__ __forceinline__ void weight_top2(float x, int& n0, int& n1,
                                            float& w0, float& w1)
{
    const float PI_F  = 3.14159265358979323846f;
    const float INV_H = 2.8647913f;           // 18 / (2*pi)
    const float H     = 0.34906585f;          // 2*pi / 18
    const float INV_T = 100.0f;
    float u = (x + PI_F) * INV_H;             // in [0, 18]
    n0 = (int)floorf(u);
    n0 = n0 < 0 ? 0 : (n0 > NB - 1 ? NB - 1 : n0);
    float f  = u - (float)n0 - 0.5f;          // [-0.5, 0.5]
    float af = fabsf(f);
    n1 = n0 + (f >= 0.0f ? 1 : -1);
    float e;
    if (n1 < 0) {                             // reference's unwrapped low edge: w1 ~ 7e-16
        e = 0.0f; n1 = NB;                    // dump row (rows >= 18 never extracted)
    } else {
        if (n1 == NB) n1 = 0;                 // positive wrap: same gap formula
        e = __expf(-(H * (1.0f - 2.0f * af)) * INV_T);
    }
    w0 = 1.0f / (1.0f + e);
    w1 = 1.0f - w0;
}

// ---------------------------------------------------------------------------
// Stage 1: block = (bc, s, tc). ampT staged ONCE, reused across all 20 p.
// Per pair: zero W | scatter weights | MFMA + dump acc into Wl rows>=18 |
// next-pair phase reduces kh in LDS and streams ONE partial per element to ws.
// No atomics anywhere.
// ---------------------------------------------------------------------------
__global__ __launch_bounds__(NTH)
void mi_partial_kernel(const float* __restrict__ phase,
                       const float* __restrict__ amp,
                       float* __restrict__ ws)
{
    __shared__ _Float16 Wl[2][32 * WSTR];     // rows 0..17: W; rows 18+: f32 dump scratch
    __shared__ _Float16 ampT[32 * WSTR];      // rows 30,31 uninit (cols never extracted)

    const int tid = threadIdx.x;
    const int blk = blockIdx.x;
    const int tc  = blk & (NTC - 1);
    const int s   = (blk >> 3) & (SS - 1);
    const int bc  = blk >> 5;                 // b*CC + c

    const float* am  = amp   + (size_t)bc * (AA * SS * TT) + (size_t)s * TT + tc * TC;
    const float* phb = phase + (size_t)(bc * PP) * (SS * TT) + (size_t)s * TT + tc * TC;
    float* ws_blk = ws + ((size_t)(bc * SS + s) * NTC + tc) * (PP * 18 * 32); // [p][18][32]

    const int wv   = tid >> 6;                // 0..3
    const int lane = tid & 63;
    const int mpl  = wv >> 1;                 // wave's local p within pair
    const int mkh  = wv & 1;                  // wave's K-half of the chunk
    const int mrow = lane & 31;               // A n-row / B a-col
    const int mlh  = lane >> 5;

    // ---- stage amp chunk transposed -> f16 ampT[a][tt] (once per block) ----
    for (int i = tid; i < AA * (TC / 4); i += NTH) {
        int a = i >> 6;                       // TC/4 == 64
        int q = i & 63;
        const float4 v = *(const float4*)&am[(size_t)a * (SS * TT) + q * 4];
        half4_t h = { (_Float16)v.x, (_Float16)v.y, (_Float16)v.z, (_Float16)v.w };
        *(half4_t*)&ampT[a * WSTR + q * 4] = h;
    }

    // ---- register-prefetch phase values for pair 0 ----
    float phv[2];
    phv[0] = phb[(size_t)0 * (SS * TT) + tid];
    phv[1] = phb[(size_t)1 * (SS * TT) + tid];

    const f32x16 kZero = {};
    f32x16 acc = {};

    for (int pp = 0; pp < NPAIR; ++pp) {
        // ---- phase A: zero W rows 0..17 + reduce-store(pp-1) + prefetch(pp+1)
        float nphv0 = 0.0f, nphv1 = 0.0f;
        if (pp + 1 < NPAIR) {                 // issue global loads earliest
            nphv0 = phb[(size_t)((pp + 1) * 2 + 0) * (SS * TT) + tid];
            nphv1 = phb[(size_t)((pp + 1) * 2 + 1) * (SS * TT) + tid];
        }
        if (pp > 0) {                         // kh-reduce in LDS, stream to ws
            for (int j = tid; j < 2 * 576; j += NTH) {
                int pl = j / 576;
                int rj = j - pl * 576;        // row*32 + col
                const float* dmp = (const float*)&Wl[pl][0] + DUMPF;
                float v = dmp[rj] + dmp[576 + rj];
                ws_blk[(size_t)((pp - 1) * 2 + pl) * 576 + rj] = v;
            }
        }
        for (int i = tid; i < 2 * 585; i += NTH) {   // 585 uint4 = 18*260 f16 (rows 0..17 only)
            int pl = i / 585;
            int w  = i - pl * 585;
            ((uint4*)&Wl[pl][0])[w] = make_uint4(0u, 0u, 0u, 0u);
        }
        __syncthreads();                      // bar1: zero done, dump reads done

        // ---- phase B: weights + scatter (expf hides prefetch/store drain) ----
        #pragma unroll
        for (int k = 0; k < 2; ++k) {
            int n0, n1; float w0, w1;
            weight_top2(phv[k], n0, n1, w0, w1);
            Wl[k][n0 * WSTR + tid] = (_Float16)w0;
            Wl[k][n1 * WSTR + tid] = (_Float16)w1;   // n1==18 garbage lands in dump
        }                                            //   region, rewritten by dump below
        phv[0] = nphv0; phv[1] = nphv1;
        __syncthreads();                      // bar2: W ready (ampT ready on pp==0 too)

        // ---- phase C: 8 K-steps of 32x32x16 MFMA, then dump acc to LDS ----
        #pragma unroll
        for (int ks = 0; ks < 8; ++ks) {
            int t0 = mkh * 128 + ks * 16 + mlh * 8;
            const _Float16* Ab = &Wl[mpl][mrow * WSTR + t0];   // rows>=18 garbage: OK,
            const _Float16* Bb = &ampT[mrow * WSTR + t0];      // MFMA rows independent
            half4_t a0 = *(const half4_t*)Ab;
            half4_t a1 = *(const half4_t*)(Ab + 4);
            half4_t b0 = *(const half4_t*)Bb;
            half4_t b1 = *(const half4_t*)(Bb + 4);
            half8_t av = __builtin_shufflevector(a0, a1, 0, 1, 2, 3, 4, 5, 6, 7);
            half8_t bv = __builtin_shufflevector(b0, b1, 0, 1, 2, 3, 4, 5, 6, 7);
            acc = __builtin_amdgcn_mfma_f32_32x32x16_f16(av, bv, acc, 0, 0, 0);
        }
        {   // dump: Wl[mpl] rows>=18 as float[kh][18][32]
            float* dmp = (float*)&Wl[mpl][0] + DUMPF + mkh * 576;
            #pragma unroll
            for (int r = 0; r < 16; ++r) {
                int row = (r & 3) + 8 * (r >> 2) + 4 * mlh;  // HW-verified C/D layout
                if (row < NB) dmp[row * 32 + mrow] = acc[r];
            }
        }
        acc = kZero;
        __syncthreads();                      // bar3: dump visible; W reads done pre-zero
    }

    // ---- tail: reduce-store for the last pair ----
    for (int j = tid; j < 2 * 576; j += NTH) {
        int pl = j / 576;
        int rj = j - pl * 576;
        const float* dmp = (const float*)&Wl[pl][0] + DUMPF;
        float v = dmp[rj] + dmp[576 + rj];
        ws_blk[(size_t)((NPAIR - 1) * 2 + pl) * 576 + rj] = v;
    }
}

// ---------------------------------------------------------------------------
// Stage 2: sum 8 tc-partials per element + entropy. Thread per (bcs, p, a).
// ---------------------------------------------------------------------------
__global__ __launch_bounds__(256)
void mi_entropy_kernel(const float* __restrict__ ws, float* __restrict__ out)
{
    int i = blockIdx.x * 256 + threadIdx.x;   // 0 .. 76799
    int a  = i % AA;
    int rp = i / AA;                          // bcs*PP + p
    int p  = rp % PP;
    int bcs = rp / PP;

    float v[NB];
    #pragma unroll
    for (int n = 0; n < NB; ++n) v[n] = 0.0f;
    #pragma unroll
    for (int tcb = 0; tcb < NTC; ++tcb) {
        const float* q = ws + ((size_t)(bcs * NTC + tcb) * PP + p) * 576 + a;
        #pragma unroll
        for (int n = 0; n < NB; ++n) v[n] += q[n * 32];
    }
    float tot = 0.0f;
    #pragma unroll
    for (int n = 0; n < NB; ++n) tot += v[n];
    float inv = 1.0f / (tot + 1e-10f);
    float ne = 0.0f;
    #pragma unroll
    for (int n = 0; n < NB; ++n) {
        float pv = fmaxf(v[n] * inv, 1e-10f);
        ne += pv * logf(pv);
    }
    out[i] = 1.0f + ne * 0.345975362f;        // 1/log(18)
}

// ---------------------------------------------------------------------------
// Fallback (round-2 single-kernel path, known-good 78 us) if ws too small.
// ---------------------------------------------------------------------------
__global__ __launch_bounds__(NTH)
void mi_mfma_kernel(const float* __restrict__ phase,
                    const float* __restrict__ amp,
                    float* __restrict__ out)
{
    __shared__ _Float16 Wl[2][32 * WSTR];
    __shared__ _Float16 ampT[32 * WSTR];

    const int tid  = threadIdx.x;
    const int blk  = blockIdx.x;
    const int pg   = blk % NPG;
    const int s    = (blk / NPG) & (SS - 1);
    const int bc   = blk / (NPG * SS);

    const float* am = amp + (size_t)bc * (AA * SS * TT) + (size_t)s * TT;

    const int wv   = tid >> 6;
    const int lane = tid & 63;
    const int mpl  = wv >> 1;
    const int mkh  = wv & 1;
    const int mrow = lane & 31;
    const int mlh  = lane >> 5;

    f32x16 acc = {};

    for (int c = 0; c < NTC; ++c) {
        __syncthreads();
        for (int i = tid; i < 2 * 585; i += NTH) {
            int pl = i / 585;
            int w  = i - pl * 585;
            ((uint4*)&Wl[pl][0])[w] = make_uint4(0u, 0u, 0u, 0u);
        }
        for (int i = tid; i < AA * (TC / 4); i += NTH) {
            int a = i >> 6;
            int q = i & 63;
            const float4 v = *(const float4*)&am[(size_t)a * (SS * TT) + c * TC + q * 4];
            half4_t h = { (_Float16)v.x, (_Float16)v.y, (_Float16)v.z, (_Float16)v.w };
            *(half4_t*)&ampT[a * WSTR + q * 4] = h;
        }
        __syncthreads();
        for (int k = 0; k < 2; ++k) {
            int it = tid + (k << 8);
            int pl = it >> 8;
            int tt = it & (TC - 1);
            int p  = pg * 2 + pl;
            float x = phase[((size_t)(bc * PP + p) * SS + s) * TT + c * TC + tt];
            int n0, n1; float w0, w1;
            weight_top2(x, n0, n1, w0, w1);
            Wl[pl][n0 * WSTR + tt] = (_Float16)w0;
            Wl[pl][n1 * WSTR + tt] = (_Float16)w1;
        }
        __syncthreads();
        #pragma unroll
        for (int ks = 0; ks < 8; ++ks) {
            int t0 = mkh * 128 + ks * 16 + mlh * 8;
            const _Float16* Ab = &Wl[mpl][mrow * WSTR + t0];
            const _Float16* Bb = &ampT[mrow * WSTR + t0];
            half4_t a0 = *(const half4_t*)Ab;
            half4_t a1 = *(const half4_t*)(Ab + 4);
            half4_t b0 = *(const half4_t*)Bb;
            half4_t b1 = *(const half4_t*)(Bb + 4);
            half8_t av = __builtin_shufflevector(a0, a1, 0, 1, 2, 3, 4, 5, 6, 7);
            half8_t bv = __builtin_shufflevector(b0, b1, 0, 1, 2, 3, 4, 5, 6, 7);
            acc = __builtin_amdgcn_mfma_f32_32x32x16_f16(av, bv, acc, 0, 0, 0);
        }
    }
    __syncthreads();

    float* dist = (float*)&ampT[0];
    #pragma unroll
    for (int r = 0; r < 16; ++r) {
        int row = (r & 3) + 8 * (r >> 2) + 4 * mlh;
        if (row < NB)
            dist[(((mpl << 1) | mkh) * NB + row) * 33 + mrow] = acc[r];
    }
    __syncthreads();

    if (tid < 2 * AA) {
        int pl = tid / AA;
        int a  = tid - pl * AA;
        float dn[NB], tot = 0.0f;
        #pragma unroll
        for (int n = 0; n < NB; ++n) {
            dn[n] = dist[((pl * 2 + 0) * NB + n) * 33 + a]
                  + dist[((pl * 2 + 1) * NB + n) * 33 + a];
            tot += dn[n];
        }
        float inv = 1.0f / (tot + 1e-10f);
        float ne = 0.0f;
        #pragma unroll
        for (int n = 0; n < NB; ++n) {
            float pv = fmaxf(dn[n] * inv, 1e-10f);
            ne += pv * logf(pv);
        }
        int p = pg * 2 + pl;
        out[((size_t)bc * SS + s) * (PP * AA) + p * AA + a] = 1.0f + ne * 0.345975362f;
    }
}

extern "C" void kernel_launch(void* const* d_in, const int* in_sizes, int n_in,
                              void* d_out, int out_size, void* d_ws, size_t ws_size,
                              hipStream_t stream)
{
    const float* phase = (const float*)d_in[0];
    const float* amp   = (const float*)d_in[1];
    float* out = (float*)d_out;

    if (ws_size >= WS2_BYTES) {
        float* ws = (float*)d_ws;             // every read slot is written: no memset
        hipLaunchKernelGGL(mi_partial_kernel, dim3(BB * CC * SS * NTC), dim3(NTH),
                           0, stream, phase, amp, ws);
        hipLaunchKernelGGL(mi_entropy_kernel, dim3((BB * CC * SS * PP * AA) / 256),
                           dim3(256), 0, stream, ws, out);
    } else {
        hipLaunchKernelGGL(mi_mfma_kernel, dim3(BB * CC * SS * NPG), dim3(NTH),
                           0, stream, phase, amp, out);
    }
}

// Round 5
// 53.830 us; speedup vs baseline: 2.4318x; 1.3029x over previous
//
#include <hip/hip_runtime.h>
#include <math.h>
#include <stdint.h>

// Problem dims (fixed by reference setup_inputs)
#define BB 4
#define CC 8
#define PP 20
#define AA 30
#define SS 4
#define TT 2048
#define NB 18

#define TC 256                  // t-chunk per stage-1 block
#define NTC (TT / TC)           // 8 t-chunks
#define NPG 10                  // (fallback kernel) p-groups of 2
#define WSTR 260                // f16 row stride: 520 B -> 2-way bank alias (free), 8B-aligned
#define WROWS 19                // rows 0..17 = W, row 18 = garbage/dump row
#define NTH 256                 // 4 waves = 4 K-quarters

// Partial dist workspace: [bcs=128][tc=8][p=20][row=18][col=32] f32
#define WS2_BYTES ((size_t)BB * CC * SS * NTC * PP * 18 * 32 * 4)   // 47,185,920

// Relaxed barrier (T4): LDS-visibility only; global loads/stores stay in flight.
#define BAR() do { asm volatile("s_waitcnt lgkmcnt(0)" ::: "memory"); \
                   __builtin_amdgcn_s_barrier(); } while (0)

typedef _Float16 half4_t __attribute__((ext_vector_type(4)));
typedef _Float16 half8_t __attribute__((ext_vector_type(8)));
typedef float f32x16 __attribute__((ext_vector_type(16)));

__device__ __forceinline__ void weight_top2(float x, int& n0, int& n1,
                                            float& w0, float& w1)
{
    const float PI_F  = 3.14159265358979323846f;
    const float INV_H = 2.8647913f;           // 18 / (2*pi)
    const float H     = 0.34906585f;          // 2*pi / 18
    const float INV_T = 100.0f;
    float u = (x + PI_F) * INV_H;             // in [0, 18]
    n0 = (int)floorf(u);
    n0 = n0 < 0 ? 0 : (n0 > NB - 1 ? NB - 1 : n0);
    float f  = u - (float)n0 - 0.5f;          // [-0.5, 0.5]
    float af = fabsf(f);
    n1 = n0 + (f >= 0.0f ? 1 : -1);
    float e;
    if (n1 < 0) {                             // reference's unwrapped low edge: w1 ~ 7e-16
        e = 0.0f; n1 = NB;                    // garbage row 18 (never extracted)
    } else {
        if (n1 == NB) n1 = 0;                 // positive wrap: same gap formula
        e = __expf(-(H * (1.0f - 2.0f * af)) * INV_T);
    }
    w0 = 1.0f / (1.0f + e);
    w1 = 1.0f - w0;
}

// ---------------------------------------------------------------------------
// Stage 1: block = (bc, s, tc); 4 waves = 4 K-quarters; 1 p per iteration.
// ampT staged once. Per iter: {reduce-store(p-1) ∥ prefetch(p+1) ∥ unwrite ∥
// scatter} BAR {4 MFMA, dump} BAR. ~34.7 KB LDS -> 4 blocks/CU, no tail.
// ---------------------------------------------------------------------------
__global__ __launch_bounds__(NTH)
void mi_partial_kernel(const float* __restrict__ phase,
                       const float* __restrict__ amp,
                       float* __restrict__ ws)
{
    __shared__ _Float16 Wl[WROWS * WSTR];               // 9,880 B
    __shared__ _Float16 ampT[AA * WSTR];                // 15,600 B
    __shared__ __align__(16) float dmp[4 * 18 * 32];    // 9,216 B

    const int tid = threadIdx.x;
    const int blk = blockIdx.x;
    const int tc  = blk & (NTC - 1);
    const int s   = (blk >> 3) & (SS - 1);
    const int bc  = blk >> 5;                 // b*CC + c

    const float* am  = amp   + (size_t)bc * (AA * SS * TT) + (size_t)s * TT + tc * TC;
    const float* phb = phase + (size_t)(bc * PP) * (SS * TT) + (size_t)s * TT + tc * TC;
    float* ws_blk = ws + ((size_t)(bc * SS + s) * NTC + tc) * (PP * 576); // [p][18][32]

    const int kh   = tid >> 6;                // wave = K-quarter (0..3)
    const int lane = tid & 63;
    const int mrow = lane & 31;
    const int mlh  = lane >> 5;
    const int arow = mrow < WROWS ? mrow : (WROWS - 1);  // A-row clamp: lanes>=19 ->
    const int brow = mrow < AA    ? mrow : (AA - 1);     //  garbage row (broadcast);
                                                         // D rows>=18 / cols>=30 unused
    // ---- stage amp chunk transposed -> f16 ampT[a][tt] (once per block) ----
    for (int i = tid; i < AA * (TC / 4); i += NTH) {
        int a = i >> 6;                       // TC/4 == 64
        int q = i & 63;
        const float4 v = *(const float4*)&am[(size_t)a * (SS * TT) + q * 4];
        half4_t h = { (_Float16)v.x, (_Float16)v.y, (_Float16)v.z, (_Float16)v.w };
        *(half4_t*)&ampT[a * WSTR + q * 4] = h;
    }
    // ---- zero W rows 0..17 once (row 18 garbage-tolerated) ----
    for (int i = tid; i < 585; i += NTH)      // 585 uint4 = 18*260 f16
        ((uint4*)Wl)[i] = make_uint4(0u, 0u, 0u, 0u);

    float phv = phb[tid];                     // p=0 phase value for this column
    BAR();

    const f32x16 kZero = {};
    f32x16 acc = {};
    int pn0 = 0, pn1 = 0;

    for (int p = 0; p < PP; ++p) {
        // ---- phase AB: reduce-store(p-1) + prefetch(p+1) + unwrite + scatter
        float nphv = 0.0f;
        if (p + 1 < PP)
            nphv = phb[(size_t)(p + 1) * (SS * TT) + tid];  // stays in flight past BARs
        if (p > 0) {
            if (tid < 144) {                  // kh-reduce dump, stream f4 to ws
                const float4* d4 = (const float4*)dmp;
                float4 v = d4[tid];
                float4 v1 = d4[144 + tid], v2 = d4[288 + tid], v3 = d4[432 + tid];
                v.x += v1.x + v2.x + v3.x;  v.y += v1.y + v2.y + v3.y;
                v.z += v1.z + v2.z + v3.z;  v.w += v1.w + v2.w + v3.w;
                *(float4*)&ws_blk[(size_t)(p - 1) * 576 + tid * 4] = v;
            }
            Wl[pn0 * WSTR + tid] = (_Float16)0.0f;   // unwrite own column
            Wl[pn1 * WSTR + tid] = (_Float16)0.0f;
        }
        {
            int n0, n1; float w0, w1;
            weight_top2(phv, n0, n1, w0, w1);
            Wl[n0 * WSTR + tid] = (_Float16)w0;
            Wl[n1 * WSTR + tid] = (_Float16)w1;      // n1==18 lands in garbage row
            pn0 = n0; pn1 = n1;
        }
        phv = nphv;
        BAR();                                 // W ready (LDS only; no vmcnt drain)
        __builtin_amdgcn_sched_barrier(0);

        // ---- phase C: 4 MFMA K-steps (this wave's K-quarter), dump to dmp ----
        #pragma unroll
        for (int ks = 0; ks < 4; ++ks) {
            int t0 = kh * 64 + ks * 16 + mlh * 8;
            const _Float16* Ab = &Wl[arow * WSTR + t0];
            const _Float16* Bb = &ampT[brow * WSTR + t0];
            half4_t a0 = *(const half4_t*)Ab;
            half4_t a1 = *(const half4_t*)(Ab + 4);
            half4_t b0 = *(const half4_t*)Bb;
            half4_t b1 = *(const half4_t*)(Bb + 4);
            half8_t av = __builtin_shufflevector(a0, a1, 0, 1, 2, 3, 4, 5, 6, 7);
            half8_t bv = __builtin_shufflevector(b0, b1, 0, 1, 2, 3, 4, 5, 6, 7);
            acc = __builtin_amdgcn_mfma_f32_32x32x16_f16(av, bv, acc, 0, 0, 0);
        }
        #pragma unroll
        for (int r = 0; r < 16; ++r) {
            int row = (r & 3) + 8 * (r >> 2) + 4 * mlh;  // HW-verified C/D layout
            if (row < NB) dmp[kh * 576 + row * 32 + mrow] = acc[r];
        }
        acc = kZero;
        BAR();                                 // dump visible for next reduce
    }

    // ---- tail: reduce-store for p = 19 ----
    if (tid < 144) {
        const float4* d4 = (const float4*)dmp;
        float4 v = d4[tid];
        float4 v1 = d4[144 + tid], v2 = d4[288 + tid], v3 = d4[432 + tid];
        v.x += v1.x + v2.x + v3.x;  v.y += v1.y + v2.y + v3.y;
        v.z += v1.z + v2.z + v3.z;  v.w += v1.w + v2.w + v3.w;
        *(float4*)&ws_blk[(size_t)(PP - 1) * 576 + tid * 4] = v;
    }
}

// ---------------------------------------------------------------------------
// Stage 2: block per (bcs,p); 64 lanes = (tc 8) x (col-group 8); float4 loads,
// shfl-xor tc-tree, 8 lanes compute entropy for 4 cols each.
// ---------------------------------------------------------------------------
__global__ __launch_bounds__(64)
void mi_entropy_kernel(const float* __restrict__ ws, float* __restrict__ out)
{
    const int rp  = blockIdx.x;               // bcs*PP + p
    const int p   = rp % PP;
    const int bcs = rp / PP;
    const int l   = threadIdx.x;
    const int g   = l & 7;                    // col-group: cols g*4 .. g*4+3
    const int tcb = l >> 3;                   // tc

    const float* q = ws + (((size_t)bcs * NTC + tcb) * PP + p) * 576 + g * 4;
    float4 v[NB];
    #pragma unroll
    for (int n = 0; n < NB; ++n) v[n] = *(const float4*)&q[n * 32];

    #pragma unroll
    for (int n = 0; n < NB; ++n) {            // reduce over tc: lanes 8/16/32 apart
        #pragma unroll
        for (int m = 8; m < 64; m <<= 1) {
            v[n].x += __shfl_xor(v[n].x, m);
            v[n].y += __shfl_xor(v[n].y, m);
            v[n].z += __shfl_xor(v[n].z, m);
            v[n].w += __shfl_xor(v[n].w, m);
        }
    }

    if (l < 8) {                              // g == l here
        #pragma unroll
        for (int c = 0; c < 4; ++c) {
            int a = l * 4 + c;
            if (a < AA) {
                float tot = 0.0f;
                #pragma unroll
                for (int n = 0; n < NB; ++n)
                    tot += (c == 0 ? v[n].x : c == 1 ? v[n].y : c == 2 ? v[n].z : v[n].w);
                float inv = 1.0f / (tot + 1e-10f);
                float ne = 0.0f;
                #pragma unroll
                for (int n = 0; n < NB; ++n) {
                    float pv = (c == 0 ? v[n].x : c == 1 ? v[n].y : c == 2 ? v[n].z : v[n].w) * inv;
                    pv = fmaxf(pv, 1e-10f);
                    ne += pv * logf(pv);
                }
                out[(size_t)rp * AA + a] = 1.0f + ne * 0.345975362f;  // 1/log(18)
            }
        }
    }
}

// ---------------------------------------------------------------------------
// Fallback (round-2 single-kernel path, known-good 78 us) if ws too small.
// ---------------------------------------------------------------------------
__global__ __launch_bounds__(NTH)
void mi_mfma_kernel(const float* __restrict__ phase,
                    const float* __restrict__ amp,
                    float* __restrict__ out)
{
    __shared__ _Float16 Wfb[2][32 * WSTR];
    __shared__ _Float16 ampT[32 * WSTR];

    const int tid  = threadIdx.x;
    const int blk  = blockIdx.x;
    const int pg   = blk % NPG;
    const int s    = (blk / NPG) & (SS - 1);
    const int bc   = blk / (NPG * SS);

    const float* am = amp + (size_t)bc * (AA * SS * TT) + (size_t)s * TT;

    const int wv   = tid >> 6;
    const int lane = tid & 63;
    const int mpl  = wv >> 1;
    const int mkh  = wv & 1;
    const int mrow = lane & 31;
    const int mlh  = lane >> 5;

    f32x16 acc = {};

    for (int c = 0; c < NTC; ++c) {
        __syncthreads();
        for (int i = tid; i < 2 * 585; i += NTH) {
            int pl = i / 585;
            int w  = i - pl * 585;
            ((uint4*)&Wfb[pl][0])[w] = make_uint4(0u, 0u, 0u, 0u);
        }
        for (int i = tid; i < AA * (TC / 4); i += NTH) {
            int a = i >> 6;
            int q = i & 63;
            const float4 v = *(const float4*)&am[(size_t)a * (SS * TT) + c * TC + q * 4];
            half4_t h = { (_Float16)v.x, (_Float16)v.y, (_Float16)v.z, (_Float16)v.w };
            *(half4_t*)&ampT[a * WSTR + q * 4] = h;
        }
        __syncthreads();
        for (int k = 0; k < 2; ++k) {
            int it = tid + (k << 8);
            int pl = it >> 8;
            int tt = it & (TC - 1);
            int p  = pg * 2 + pl;
            float x = phase[((size_t)(bc * PP + p) * SS + s) * TT + c * TC + tt];
            int n0, n1; float w0, w1;
            weight_top2(x, n0, n1, w0, w1);
            Wfb[pl][n0 * WSTR + tt] = (_Float16)w0;
            Wfb[pl][n1 * WSTR + tt] = (_Float16)w1;
        }
        __syncthreads();
        #pragma unroll
        for (int ks = 0; ks < 8; ++ks) {
            int t0 = mkh * 128 + ks * 16 + mlh * 8;
            const _Float16* Ab = &Wfb[mpl][mrow * WSTR + t0];
            const _Float16* Bb = &ampT[mrow * WSTR + t0];
            half4_t a0 = *(const half4_t*)Ab;
            half4_t a1 = *(const half4_t*)(Ab + 4);
            half4_t b0 = *(const half4_t*)Bb;
            half4_t b1 = *(const half4_t*)(Bb + 4);
            half8_t av = __builtin_shufflevector(a0, a1, 0, 1, 2, 3, 4, 5, 6, 7);
            half8_t bv = __builtin_shufflevector(b0, b1, 0, 1, 2, 3, 4, 5, 6, 7);
            acc = __builtin_amdgcn_mfma_f32_32x32x16_f16(av, bv, acc, 0, 0, 0);
        }
    }
    __syncthreads();

    float* dist = (float*)&ampT[0];
    #pragma unroll
    for (int r = 0; r < 16; ++r) {
        int row = (r & 3) + 8 * (r >> 2) + 4 * mlh;
        if (row < NB)
            dist[(((mpl << 1) | mkh) * NB + row) * 33 + mrow] = acc[r];
    }
    __syncthreads();

    if (tid < 2 * AA) {
        int pl = tid / AA;
        int a  = tid - pl * AA;
        float dn[NB], tot = 0.0f;
        #pragma unroll
        for (int n = 0; n < NB; ++n) {
            dn[n] = dist[((pl * 2 + 0) * NB + n) * 33 + a]
                  + dist[((pl * 2 + 1) * NB + n) * 33 + a];
            tot += dn[n];
        }
        float inv = 1.0f / (tot + 1e-10f);
        float ne = 0.0f;
        #pragma unroll
        for (int n = 0; n < NB; ++n) {
            float pv = fmaxf(dn[n] * inv, 1e-10f);
            ne += pv * logf(pv);
        }
        int p = pg * 2 + pl;
        out[((size_t)bc * SS + s) * (PP * AA) + p * AA + a] = 1.0f + ne * 0.345975362f;
    }
}

extern "C" void kernel_launch(void* const* d_in, const int* in_sizes, int n_in,
                              void* d_out, int out_size, void* d_ws, size_t ws_size,
                              hipStream_t stream)
{
    const float* phase = (const float*)d_in[0];
    const float* amp   = (const float*)d_in[1];
    float* out = (float*)d_out;

    if (ws_size >= WS2_BYTES) {
        float* ws = (float*)d_ws;             // every read slot is written: no memset
        hipLaunchKernelGGL(mi_partial_kernel, dim3(BB * CC * SS * NTC), dim3(NTH),
                           0, stream, phase, amp, ws);
        hipLaunchKernelGGL(mi_entropy_kernel, dim3(BB * CC * SS * PP), dim3(64),
                           0, stream, ws, out);
    } else {
        hipLaunchKernelGGL(mi_mfma_kernel, dim3(BB * CC * SS * NPG), dim3(NTH),
                           0, stream, phase, amp, out);
    }
}

// Round 6
// 44.406 us; speedup vs baseline: 2.9479x; 1.2122x over previous
//
#include <hip/hip_runtime.h>
#include <math.h>
#include <stdint.h>

// Problem dims (fixed by reference setup_inputs)
#define BB 4
#define CC 8
#define PP 20
#define AA 30
#define SS 4
#define TT 2048
#define NB 18

#define TC 256                  // t-chunk (K-slab) per iteration
#define NCH (TT / TC)           // 8 chunks
#define PG 4                    // p's per block = waves per block
#define NPG (PP / PG)           // 5 p-groups
#define WSTR 260                // f16 row stride: 520 B -> 2-row bank step 2 (2-way free), 8B-aligned
#define WROWS 19                // rows 0..17 = W, row 18 = dump row for the unwrapped edge
#define NTH 256                 // 4 waves; wave w owns p = pg*4 + w

// Relaxed barrier: LDS-visibility only; global loads stay in flight across it.
#define BAR() do { asm volatile("s_waitcnt lgkmcnt(0)" ::: "memory"); \
                   __builtin_amdgcn_s_barrier(); } while (0)

typedef _Float16 half4_t __attribute__((ext_vector_type(4)));
typedef _Float16 half8_t __attribute__((ext_vector_type(8)));
typedef float f32x16 __attribute__((ext_vector_type(16)));

__device__ __forceinline__ void weight_top2(float x, int& n0, int& n1,
                                            float& w0, float& w1)
{
    const float PI_F  = 3.14159265358979323846f;
    const float INV_H = 2.8647913f;           // 18 / (2*pi)
    const float H     = 0.34906585f;          // 2*pi / 18
    const float INV_T = 100.0f;
    float u = (x + PI_F) * INV_H;             // in [0, 18]
    n0 = (int)floorf(u);
    n0 = n0 < 0 ? 0 : (n0 > NB - 1 ? NB - 1 : n0);
    float f  = u - (float)n0 - 0.5f;          // [-0.5, 0.5]
    float af = fabsf(f);
    n1 = n0 + (f >= 0.0f ? 1 : -1);
    float e;
    if (n1 < 0) {                             // reference's unwrapped low edge: w1 ~ 7e-16
        e = 0.0f; n1 = NB;                    // row 18 gets 0.0 (never extracted)
    } else {
        if (n1 == NB) n1 = 0;                 // positive wrap: same gap formula
        e = __expf(-(H * (1.0f - 2.0f * af)) * INV_T);
    }
    w0 = 1.0f / (1.0f + e);
    w1 = 1.0f - w0;
}

// ---------------------------------------------------------------------------
// Single fused kernel. Block = (bc, s, pgroup); wave w owns p = pg*4+w fully:
// scatter into wave-PRIVATE W (no inter-wave sync needed), K-accumulate over
// all 8 chunks in registers, dump + entropy + store, all wave-local.
// Shared state = double-buffered ampT only -> ONE relaxed barrier per chunk.
// ---------------------------------------------------------------------------
__global__ __launch_bounds__(NTH)
void mi_fused_kernel(const float* __restrict__ phase,
                     const float* __restrict__ amp,
                     float* __restrict__ out)
{
    __shared__ _Float16 Wl[4][WROWS * WSTR];   // 4 x 9,880 B, wave-private tiles
    __shared__ _Float16 ampT[2][AA * WSTR];    // 2 x 15,600 B, double-buffered

    const int tid = threadIdx.x;
    const int blk = blockIdx.x;
    const int pg  = blk % NPG;                 // fastest: sharers of one amp slice
    const int s   = (blk / NPG) & (SS - 1);
    const int bc  = blk / (NPG * SS);          // b*CC + c

    const int wv   = tid >> 6;
    const int lane = tid & 63;
    const int mrow = lane & 31;
    const int mlh  = lane >> 5;
    const int arow = mrow < WROWS ? mrow : (WROWS - 1);  // A rows >=19 -> zero row 18
    const int brow = mrow < AA    ? mrow : (AA - 1);     // B rows 30,31 -> dup (unused cols)

    const int p = pg * PG + wv;                // this wave's p
    const float* am  = amp   + (size_t)bc * (AA * SS * TT) + (size_t)s * TT;
    const float* phw = phase + ((size_t)(bc * PP + p) * SS + s) * TT;
    float*       op  = out   + ((size_t)(bc * SS + s) * PP + p) * AA;

    // ---- prologue: zero own W tile, stage chunk 0, load own phase f4 ----
    {
        uint2* wz = (uint2*)&Wl[wv][0];        // 9,880 B = 1,235 uint2
        for (int i = lane; i < 1235; i += 64) wz[i] = make_uint2(0u, 0u);
    }
    #pragma unroll
    for (int j = 0; j < 8; ++j) {              // stage chunk 0 (coop, all 256 thr)
        int q = tid + j * 256;                 // quad id; 1920 = 30 rows x 64 quads
        int a = q >> 6, tq = q & 63;
        if (a < AA) {
            const float4 v = *(const float4*)&am[(size_t)a * (SS * TT) + tq * 4];
            half4_t h = { (_Float16)v.x, (_Float16)v.y, (_Float16)v.z, (_Float16)v.w };
            *(half4_t*)&ampT[0][a * WSTR + tq * 4] = h;
        }
    }
    float4 ph4 = *(const float4*)&phw[lane * 4];
    BAR();

    f32x16 acc0 = {}, acc1 = {};
    int pn0[4], pn1[4];

    for (int c = 0; c < NCH; ++c) {
        const int cb = c & 1, tb = cb ^ 1;

        // ---- issue next-chunk global loads EARLY (consumed after MFMA) ----
        float4 nph4 = {};
        float4 stg[8];
        if (c + 1 < NCH) {
            nph4 = *(const float4*)&phw[(c + 1) * TC + lane * 4];
            #pragma unroll
            for (int j = 0; j < 8; ++j) {
                int q = tid + j * 256;
                int a = q >> 6, tq = q & 63;
                int ac = a < AA ? a : (AA - 1);          // clamp: no OOB read
                stg[j] = *(const float4*)&am[(size_t)ac * (SS * TT) + (c + 1) * TC + tq * 4];
            }
        }

        // ---- unwrite previous chunk's entries, scatter this chunk's ----
        #pragma unroll
        for (int j = 0; j < 4; ++j) {
            int col = lane * 4 + j;
            if (c > 0) {
                Wl[wv][pn0[j] * WSTR + col] = (_Float16)0.0f;
                Wl[wv][pn1[j] * WSTR + col] = (_Float16)0.0f;
            }
            int n0, n1; float w0, w1;
            weight_top2(j == 0 ? ph4.x : j == 1 ? ph4.y : j == 2 ? ph4.z : ph4.w,
                        n0, n1, w0, w1);
            Wl[wv][n0 * WSTR + col] = (_Float16)w0;
            Wl[wv][n1 * WSTR + col] = (_Float16)w1;
            pn0[j] = n0; pn1[j] = n1;
        }

        // ---- 16 MFMA K-steps (wave-local; ds order guarantees scatter visible) ----
        #pragma unroll
        for (int ks = 0; ks < 16; ++ks) {
            int t0 = ks * 16 + mlh * 8;
            const _Float16* Ab = &Wl[wv][arow * WSTR + t0];
            const _Float16* Bb = &ampT[cb][brow * WSTR + t0];
            half4_t a0 = *(const half4_t*)Ab;
            half4_t a1 = *(const half4_t*)(Ab + 4);
            half4_t b0 = *(const half4_t*)Bb;
            half4_t b1 = *(const half4_t*)(Bb + 4);
            half8_t av = __builtin_shufflevector(a0, a1, 0, 1, 2, 3, 4, 5, 6, 7);
            half8_t bv = __builtin_shufflevector(b0, b1, 0, 1, 2, 3, 4, 5, 6, 7);
            if (ks & 1) acc1 = __builtin_amdgcn_mfma_f32_32x32x16_f16(av, bv, acc1, 0, 0, 0);
            else        acc0 = __builtin_amdgcn_mfma_f32_32x32x16_f16(av, bv, acc0, 0, 0, 0);
        }

        // ---- write-late: stage next chunk into the other buffer ----
        if (c + 1 < NCH) {
            #pragma unroll
            for (int j = 0; j < 8; ++j) {
                int q = tid + j * 256;
                int a = q >> 6, tq = q & 63;
                if (a < AA) {
                    half4_t h = { (_Float16)stg[j].x, (_Float16)stg[j].y,
                                  (_Float16)stg[j].z, (_Float16)stg[j].w };
                    *(half4_t*)&ampT[tb][a * WSTR + tq * 4] = h;
                }
            }
        }
        ph4 = nph4;
        BAR();   // syncs ampT only: my reads of [cb] done; my writes to [tb] visible
    }

    // ---- epilogue (wave-local): dump acc, entropy, store ----
    f32x16 acc = acc0 + acc1;
    float* dmp = (float*)&Wl[wv][0];           // own tile dead; [18][33] f32 fits
    #pragma unroll
    for (int r = 0; r < 16; ++r) {
        int row = (r & 3) + 8 * (r >> 2) + 4 * mlh;   // HW-verified C/D layout
        if (row < NB) dmp[row * 33 + mrow] = acc[r];
    }
    // wave64-coherent LDS: compiler orders ds ops + lgkmcnt; no barrier needed
    if (lane < AA) {
        float v[NB], tot = 0.0f;
        #pragma unroll
        for (int n = 0; n < NB; ++n) { v[n] = dmp[n * 33 + lane]; tot += v[n]; }
        float inv = 1.0f / (tot + 1e-10f);
        float ne = 0.0f;
        #pragma unroll
        for (int n = 0; n < NB; ++n) {
            float pv = fmaxf(v[n] * inv, 1e-10f);
            ne += pv * logf(pv);
        }
        op[lane] = 1.0f + ne * 0.345975362f;   // 1/log(18)
    }
}

extern "C" void kernel_launch(void* const* d_in, const int* in_sizes, int n_in,
                              void* d_out, int out_size, void* d_ws, size_t ws_size,
                              hipStream_t stream)
{
    const float* phase = (const float*)d_in[0];
    const float* amp   = (const float*)d_in[1];
    float* out = (float*)d_out;
    hipLaunchKernelGGL(mi_fused_kernel, dim3(BB * CC * SS * NPG), dim3(NTH),
                       0, stream, phase, amp, out);
}

// Round 7
// 30.435 us; speedup vs baseline: 4.3011x; 1.4590x over previous
//
#include <hip/hip_runtime.h>
#include <math.h>
#include <stdint.h>

// Problem dims (fixed by reference setup_inputs)
#define BB 4
#define CC 8
#define PP 20
#define AA 30
#define SS 4
#define TT 2048
#define NB 18

#define TC 128                  // t-chunk (K-slab) per iteration
#define NCH (TT / TC)           // 16 chunks
#define PG 4                    // p's per block = waves per block
#define NPG (PP / PG)           // 5 p-groups
#define WSTR 132                // f16 row stride: 264 B -> bank step 2 (2-way free), 8B-aligned
#define WROWS 19                // rows 0..17 = W, row 18 = dump row for the unwrapped edge
#define NTH 256                 // 4 waves; wave w owns p = pg*4 + w

// Relaxed barrier: LDS-visibility only; global loads stay in flight across it.
#define BAR() do { asm volatile("s_waitcnt lgkmcnt(0)" ::: "memory"); \
                   __builtin_amdgcn_s_barrier(); } while (0)

typedef _Float16 half4_t __attribute__((ext_vector_type(4)));
typedef _Float16 half8_t __attribute__((ext_vector_type(8)));
typedef float f32x16 __attribute__((ext_vector_type(16)));

__device__ __forceinline__ void weight_top2(float x, int& n0, int& n1,
                                            float& w0, float& w1)
{
    const float PI_F  = 3.14159265358979323846f;
    const float INV_H = 2.8647913f;           // 18 / (2*pi)
    const float H     = 0.34906585f;          // 2*pi / 18
    const float INV_T = 100.0f;
    float u = (x + PI_F) * INV_H;             // in [0, 18]
    n0 = (int)floorf(u);
    n0 = n0 < 0 ? 0 : (n0 > NB - 1 ? NB - 1 : n0);
    float f  = u - (float)n0 - 0.5f;          // [-0.5, 0.5]
    float af = fabsf(f);
    n1 = n0 + (f >= 0.0f ? 1 : -1);
    float e;
    if (n1 < 0) {                             // reference's unwrapped low edge: w1 ~ 7e-16
        e = 0.0f; n1 = NB;                    // row 18 gets 0.0 (never extracted)
    } else {
        if (n1 == NB) n1 = 0;                 // positive wrap: same gap formula
        e = __expf(-(H * (1.0f - 2.0f * af)) * INV_T);
    }
    w0 = 1.0f / (1.0f + e);
    w1 = 1.0f - w0;
}

// ---------------------------------------------------------------------------
// Single fused kernel. Block = (bc, s, pgroup); wave w owns p = pg*4+w fully
// (wave-private W scatter, register K-accumulation, wave-local epilogue).
// Shared state = double-buffered ampT -> ONE relaxed barrier per chunk.
// TC=128: 35.9 KB LDS -> 4 blocks/CU, all 640 blocks co-resident (no tail).
// XCD swizzle: the 5 blocks sharing an amp slice map to the SAME XCD
// (physical XCD ~ blockIdx%8 round-robin) -> slice fetched once per L2.
// ---------------------------------------------------------------------------
__global__ __launch_bounds__(NTH)
void mi_fused_kernel(const float* __restrict__ phase,
                     const float* __restrict__ amp,
                     float* __restrict__ out)
{
    __shared__ _Float16 Wl[4][WROWS * WSTR];   // 4 x 5,016 B, wave-private tiles
    __shared__ _Float16 ampT[2][AA * WSTR];    // 2 x 7,920 B, double-buffered

    const int tid = threadIdx.x;
    // ---- XCD-aware swizzle (bijective 640->640): sharing group g stays on xcd x
    const int bid = blockIdx.x;
    const int x   = bid & 7;                   // physical XCD (dispatch model)
    const int kk  = bid >> 3;                  // 0..79
    const int pg  = kk % NPG;                  // member within amp-sharing group
    const int g   = x + 8 * (kk / NPG);        // 0..127 = bc*SS + s
    const int s   = g & (SS - 1);
    const int bc  = g >> 2;                    // b*CC + c

    const int wv   = tid >> 6;
    const int lane = tid & 63;
    const int mrow = lane & 31;
    const int mlh  = lane >> 5;
    const int arow = mrow < WROWS ? mrow : (WROWS - 1);  // A rows >=19 -> zero row 18
    const int brow = mrow < AA    ? mrow : (AA - 1);     // B rows 30,31 -> dup (unused cols)

    const int p = pg * PG + wv;                // this wave's p
    const float* am  = amp   + (size_t)bc * (AA * SS * TT) + (size_t)s * TT;
    const float* phw = phase + ((size_t)(bc * PP + p) * SS + s) * TT;
    float*       op  = out   + ((size_t)(bc * SS + s) * PP + p) * AA;

    // ---- prologue: zero own W tile, stage chunk 0, load own phase f2 ----
    {
        uint2* wz = (uint2*)&Wl[wv][0];        // 5,016 B = 627 uint2
        for (int i = lane; i < 627; i += 64) wz[i] = make_uint2(0u, 0u);
    }
    #pragma unroll
    for (int j = 0; j < 4; ++j) {              // stage chunk 0: 960 quads, coop
        int q = tid + j * 256;
        int a = q >> 5, tq = q & 31;           // 32 quads per row (TC/4)
        if (a < AA) {
            const float4 v = *(const float4*)&am[(size_t)a * (SS * TT) + tq * 4];
            half4_t h = { (_Float16)v.x, (_Float16)v.y, (_Float16)v.z, (_Float16)v.w };
            *(half4_t*)&ampT[0][a * WSTR + tq * 4] = h;
        }
    }
    float2 ph2 = *(const float2*)&phw[lane * 2];
    BAR();

    f32x16 acc0 = {}, acc1 = {};
    int pn0[2], pn1[2];

    for (int c = 0; c < NCH; ++c) {
        const int cb = c & 1, tb = cb ^ 1;

        // ---- issue next-chunk global loads EARLY (consumed after MFMA) ----
        float2 nph2 = {};
        float4 stg[4];
        if (c + 1 < NCH) {
            nph2 = *(const float2*)&phw[(c + 1) * TC + lane * 2];
            #pragma unroll
            for (int j = 0; j < 4; ++j) {
                int q = tid + j * 256;
                int a = q >> 5, tq = q & 31;
                int ac = a < AA ? a : (AA - 1);          // clamp: no OOB read
                stg[j] = *(const float4*)&am[(size_t)ac * (SS * TT) + (c + 1) * TC + tq * 4];
            }
        }

        // ---- unwrite previous chunk's entries, scatter this chunk's ----
        #pragma unroll
        for (int j = 0; j < 2; ++j) {
            int col = lane * 2 + j;
            if (c > 0) {
                Wl[wv][pn0[j] * WSTR + col] = (_Float16)0.0f;
                Wl[wv][pn1[j] * WSTR + col] = (_Float16)0.0f;
            }
            int n0, n1; float w0, w1;
            weight_top2(j == 0 ? ph2.x : ph2.y, n0, n1, w0, w1);
            Wl[wv][n0 * WSTR + col] = (_Float16)w0;
            Wl[wv][n1 * WSTR + col] = (_Float16)w1;
            pn0[j] = n0; pn1[j] = n1;
        }

        // ---- 8 MFMA K-steps (wave-local; ds order makes scatter visible) ----
        #pragma unroll
        for (int ks = 0; ks < 8; ++ks) {
            int t0 = ks * 16 + mlh * 8;
            const _Float16* Ab = &Wl[wv][arow * WSTR + t0];
            const _Float16* Bb = &ampT[cb][brow * WSTR + t0];
            half4_t a0 = *(const half4_t*)Ab;
            half4_t a1 = *(const half4_t*)(Ab + 4);
            half4_t b0 = *(const half4_t*)Bb;
            half4_t b1 = *(const half4_t*)(Bb + 4);
            half8_t av = __builtin_shufflevector(a0, a1, 0, 1, 2, 3, 4, 5, 6, 7);
            half8_t bv = __builtin_shufflevector(b0, b1, 0, 1, 2, 3, 4, 5, 6, 7);
            if (ks & 1) acc1 = __builtin_amdgcn_mfma_f32_32x32x16_f16(av, bv, acc1, 0, 0, 0);
            else        acc0 = __builtin_amdgcn_mfma_f32_32x32x16_f16(av, bv, acc0, 0, 0, 0);
        }

        // ---- write-late: stage next chunk into the other buffer ----
        if (c + 1 < NCH) {
            #pragma unroll
            for (int j = 0; j < 4; ++j) {
                int q = tid + j * 256;
                int a = q >> 5, tq = q & 31;
                if (a < AA) {
                    half4_t h = { (_Float16)stg[j].x, (_Float16)stg[j].y,
                                  (_Float16)stg[j].z, (_Float16)stg[j].w };
                    *(half4_t*)&ampT[tb][a * WSTR + tq * 4] = h;
                }
            }
        }
        ph2 = nph2;
        BAR();   // syncs ampT only: my reads of [cb] done; my writes to [tb] visible
    }

    // ---- epilogue (wave-local): dump acc, entropy, store ----
    f32x16 acc = acc0 + acc1;
    float* dmp = (float*)&Wl[wv][0];           // own tile dead; [18][33] f32 fits
    #pragma unroll
    for (int r = 0; r < 16; ++r) {
        int row = (r & 3) + 8 * (r >> 2) + 4 * mlh;   // HW-verified C/D layout
        if (row < NB) dmp[row * 33 + mrow] = acc[r];
    }
    // wave64-coherent LDS: compiler orders ds ops + lgkmcnt; no barrier needed
    if (lane < AA) {
        float v[NB], tot = 0.0f;
        #pragma unroll
        for (int n = 0; n < NB; ++n) { v[n] = dmp[n * 33 + lane]; tot += v[n]; }
        float inv = 1.0f / (tot + 1e-10f);
        float ne = 0.0f;
        #pragma unroll
        for (int n = 0; n < NB; ++n) {
            float pv = fmaxf(v[n] * inv, 1e-10f);
            ne += pv * logf(pv);
        }
        op[lane] = 1.0f + ne * 0.345975362f;   // 1/log(18)
    }
}

extern "C" void kernel_launch(void* const* d_in, const int* in_sizes, int n_in,
                              void* d_out, int out_size, void* d_ws, size_t ws_size,
                              hipStream_t stream)
{
    const float* phase = (const float*)d_in[0];
    const float* amp   = (const float*)d_in[1];
    float* out = (float*)d_out;
    hipLaunchKernelGGL(mi_fused_kernel, dim3(BB * CC * SS * NPG), dim3(NTH),
                       0, stream, phase, amp, out);
}